// Round 10
// baseline (2015.965 us; speedup 1.0000x reference)
//
#include <hip/hip_runtime.h>
#include <hip/hip_fp16.h>
#include <math.h>

#define T_STEPS 8
#define F_IN    8
#define HID     32
#define KCH     5
#define PERIODS 8
#define NB      64
#define WSLD    140
#define TSLD    68
#define GB      1024   // barrier-kernel grid (multiple of 8, co-resident: 0 LDS, 4 blk/CU)
#define MSCOPE  __HIP_MEMORY_SCOPE_AGENT

__device__ __forceinline__ float sigmoidf_(float x) { return 1.f / (1.f + __expf(-x)); }
__device__ __forceinline__ float tanhf_(float x) {
    float e = __expf(2.f * x);
    return 1.f - 2.f / (e + 1.f);
}

// ---- lean two-level device barrier (8 sub-counters by XCD slot + main + gen) ----
// bar: [0..255] subs (stride 32), [256] main, [288] gen. Zeroed once per launch.
// Monotonic generation: target passed by caller. Requires gridDim.x % 8 == 0 and
// all blocks co-resident (0 LDS, low VGPR, GB=1024 -> 4 blocks/CU).
__device__ __forceinline__ void gbar_(int* bc, int target) {
    __syncthreads();
    if (threadIdx.x == 0) {
        __threadfence();
        int subsz = (int)(gridDim.x >> 3);
        int* sc = bc + (blockIdx.x & 7) * 32;
        int so = __hip_atomic_fetch_add(sc, 1, __ATOMIC_ACQ_REL, MSCOPE);
        if ((so % subsz) == subsz - 1) {
            int mo = __hip_atomic_fetch_add(bc + 256, 1, __ATOMIC_ACQ_REL, MSCOPE);
            if ((mo & 7) == 7)
                __hip_atomic_fetch_add(bc + 288, 1, __ATOMIC_RELEASE, MSCOPE);
        }
        while (__hip_atomic_load(bc + 288, __ATOMIC_RELAXED, MSCOPE) < target)
            __builtin_amdgcn_s_sleep(8);
        (void)__hip_atomic_load(bc + 288, __ATOMIC_ACQUIRE, MSCOPE);
    }
    __syncthreads();
}

// ---------------- graph setup ----------------

__global__ void k_count(const int* __restrict__ src, const int* __restrict__ dst,
                        int* __restrict__ degi, int* __restrict__ cnt, int E) {
    int e = blockIdx.x * blockDim.x + threadIdx.x;
    if (e >= E) return;
    int s = src[e], d = dst[e];
    if (s != d) {
        atomicAdd(&degi[s], 1);
        atomicAdd(&cnt[d], 1);
    }
}

__global__ void k_hist2(const int* __restrict__ cnt, int* __restrict__ hist,
                        int N, int NT) {
    __shared__ int h[256];
    int tid = threadIdx.x, blk = blockIdx.x;
    h[tid] = 0;
    __syncthreads();
    int n = blk * 256 + tid;
    if (n < N) atomicAdd(&h[min(cnt[n], 255)], 1);
    __syncthreads();
    hist[tid * NT + blk] = h[tid];
}

// exclusive scan, single block 1024 threads, 32 elems/thread; valid n <= 32768
__global__ void __launch_bounds__(1024) k_scan(const int* __restrict__ in,
                                               int* __restrict__ outp, int n) {
    __shared__ int wsum[16];
    int tid = threadIdx.x;
    int base = tid * 32;
    int v[32];
    int s = 0;
    #pragma unroll
    for (int i = 0; i < 32; ++i) {
        int idx = base + i;
        int t = (idx < n) ? in[idx] : 0;
        v[i] = t; s += t;
    }
    int lane = tid & 63, wave = tid >> 6;
    int incl = s;
    #pragma unroll
    for (int off = 1; off < 64; off <<= 1) {
        int t = __shfl_up(incl, off, 64);
        if (lane >= off) incl += t;
    }
    if (lane == 63) wsum[wave] = incl;
    __syncthreads();
    if (tid < 64) {
        int w = (tid < 16) ? wsum[tid] : 0;
        int iw = w;
        #pragma unroll
        for (int off = 1; off < 16; off <<= 1) {
            int t = __shfl_up(iw, off, 64);
            if (tid >= off) iw += t;
        }
        if (tid < 16) wsum[tid] = iw - w;
    }
    __syncthreads();
    int excl = wsum[wave] + (incl - s);
    #pragma unroll
    for (int i = 0; i < 32; ++i) {
        int idx = base + i;
        if (idx < n) outp[idx] = excl;
        excl += v[i];
    }
    if (tid == 1023) outp[n] = wsum[15] + incl;
}

__global__ void k_permscat2(const int* __restrict__ cnt, const int* __restrict__ degi,
                            const int* __restrict__ histbase,
                            int* __restrict__ perm, int* __restrict__ iperm,
                            int* __restrict__ cntp, float* __restrict__ dis,
                            int N, int NT) {
    __shared__ int key[256];
    int tid = threadIdx.x, blk = blockIdx.x;
    int n = blk * 256 + tid;
    int k = (n < N) ? min(cnt[n], 255) : -1;
    key[tid] = k;
    __syncthreads();
    if (n < N) {
        int r = 0;
        for (int j = 0; j < tid; ++j) r += (key[j] == k);
        int pos = histbase[k * NT + blk] + r;
        perm[pos] = n;
        iperm[n] = pos;
        cntp[pos] = cnt[n];
        int dg = degi[n];
        dis[n] = (dg > 0) ? rsqrtf((float)dg) : 0.f;
    }
}

__global__ void k_scatxt(const int* __restrict__ src, const int* __restrict__ dst,
                         const float* __restrict__ dis, const int* __restrict__ rowptr,
                         const int* __restrict__ iperm, int* __restrict__ fill,
                         int2* __restrict__ cv, const float* __restrict__ xall,
                         __half* __restrict__ xb, int N, int E) {
    int gsz = (int)(gridDim.x * blockDim.x);
    int gtid = blockIdx.x * blockDim.x + threadIdx.x;
    for (int e = gtid; e < E; e += gsz) {
        int s = src[e], d = dst[e];
        if (s != d) {
            float nv = -dis[s] * dis[d];
            int dp = iperm[d];
            int p = atomicAdd(&fill[dp], 1);
            cv[rowptr[dp] + p] = make_int2(iperm[s], __float_as_int(nv));
        }
    }
    for (int i = gtid; i < N * T_STEPS; i += gsz) {
        int n = i >> 3, t = i & 7;
        float4 a = *(const float4*)(xall + ((size_t)t * N + n) * 8);
        float4 b = *(const float4*)(xall + ((size_t)t * N + n) * 8 + 4);
        __half2 h[4];
        h[0] = __float22half2_rn(make_float2(a.x, a.y));
        h[1] = __float22half2_rn(make_float2(a.z, a.w));
        h[2] = __float22half2_rn(make_float2(b.x, b.y));
        h[3] = __float22half2_rn(make_float2(b.z, b.w));
        *(float4*)(xb + (size_t)iperm[n] * 64 + t * 8) = *(float4*)h;
    }
}

// ---- Laplacian phase (grid-stride, ES=2 edge split, fp16 features) ----
template <int C>
__device__ __forceinline__ void lapphase_(__half* __restrict__ outp,
                                          const __half* __restrict__ xin,
                                          const __half* __restrict__ xprev,
                                          float alpha, float beta,
                                          const int* __restrict__ rowptr,
                                          const int2* __restrict__ cv, int N) {
    constexpr int Q = C / 8;
    constexpr int W = Q * 2;
    int gsz = (int)(gridDim.x * 256);
    int total = N * W;
    for (int idx = blockIdx.x * 256 + threadIdx.x; idx < total; idx += gsz) {
        int node = idx / W;
        int r = idx % W;
        int q = r % Q, s = r / Q;
        int beg = rowptr[node], end = rowptr[node + 1];
        float a0 = 0.f, a1 = 0.f, a2 = 0.f, a3 = 0.f, a4 = 0.f, a5 = 0.f, a6 = 0.f, a7 = 0.f;
        #pragma unroll 4
        for (int j = beg + s; j < end; j += 2) {
            int2 p = cv[j];
            float nv = __int_as_float(p.y);
            float4 raw = *(const float4*)(xin + (size_t)p.x * C + q * 8);
            const __half2* h = (const __half2*)&raw;
            float2 f0 = __half22float2(h[0]);
            float2 f1 = __half22float2(h[1]);
            float2 f2 = __half22float2(h[2]);
            float2 f3 = __half22float2(h[3]);
            a0 += nv * f0.x; a1 += nv * f0.y; a2 += nv * f1.x; a3 += nv * f1.y;
            a4 += nv * f2.x; a5 += nv * f2.y; a6 += nv * f3.x; a7 += nv * f3.y;
        }
        a0 += __shfl_xor(a0, Q, 64); a1 += __shfl_xor(a1, Q, 64);
        a2 += __shfl_xor(a2, Q, 64); a3 += __shfl_xor(a3, Q, 64);
        a4 += __shfl_xor(a4, Q, 64); a5 += __shfl_xor(a5, Q, 64);
        a6 += __shfl_xor(a6, Q, 64); a7 += __shfl_xor(a7, Q, 64);
        if (s != 0) continue;
        size_t off = (size_t)node * C + q * 8;
        float r0 = alpha * a0, r1 = alpha * a1, r2 = alpha * a2, r3 = alpha * a3;
        float r4 = alpha * a4, r5 = alpha * a5, r6 = alpha * a6, r7 = alpha * a7;
        if (beta != 0.f) {
            float4 raw = *(const float4*)(xprev + off);
            const __half2* h = (const __half2*)&raw;
            float2 f0 = __half22float2(h[0]);
            float2 f1 = __half22float2(h[1]);
            float2 f2 = __half22float2(h[2]);
            float2 f3 = __half22float2(h[3]);
            r0 += beta * f0.x; r1 += beta * f0.y; r2 += beta * f1.x; r3 += beta * f1.y;
            r4 += beta * f2.x; r5 += beta * f2.y; r6 += beta * f3.x; r7 += beta * f3.y;
        }
        __half2 o[4];
        o[0] = __float22half2_rn(make_float2(r0, r1));
        o[1] = __float22half2_rn(make_float2(r2, r3));
        o[2] = __float22half2_rn(make_float2(r4, r5));
        o[3] = __float22half2_rn(make_float2(r6, r7));
        *(float4*)(outp + off) = *(float4*)o;
    }
}

// ---- fused Chebyshev chain: 4 lap phases, 3 internal device barriers ----
template <int C>
__global__ void __launch_bounds__(256, 4) k_lapquad(
    __half* __restrict__ T0, __half* __restrict__ T1, __half* __restrict__ T2,
    __half* __restrict__ T3, __half* __restrict__ T4,
    const int* __restrict__ rowptr, const int2* __restrict__ cv,
    int* bar, int bar_base, int N) {
    lapphase_<C>(T1, T0, nullptr, 1.f,  0.f, rowptr, cv, N);
    gbar_(bar, bar_base + 1);
    lapphase_<C>(T2, T1, T0,      2.f, -1.f, rowptr, cv, N);
    gbar_(bar, bar_base + 2);
    lapphase_<C>(T3, T2, T1,      2.f, -1.f, rowptr, cv, N);
    gbar_(bar, bar_base + 3);
    lapphase_<C>(T4, T3, T2,      2.f, -1.f, rowptr, cv, N);
}

// ---------------- fused gate GEMM + LSTM pointwise (+ output head at t=T-1) --
__global__ void __launch_bounds__(256) k_step(
    const __half* __restrict__ xb, const __half* __restrict__ TXB,
    __half* __restrict__ THall, float* __restrict__ Cst,
    const float* __restrict__ Wx, const float* __restrict__ Wh,
    const float* __restrict__ w_c, const float* __restrict__ bg,
    const float* __restrict__ W_lin, const float* __restrict__ b_lin,
    const int* __restrict__ perm, float* __restrict__ out,
    int t, int withH, int doOut, int N) {
    __shared__ float Ws[40 * WSLD];
    __shared__ float Ts[40 * TSLD];
    int tid = threadIdx.x;
    int base = blockIdx.x * NB;
    int og = tid & 15;
    int o0 = og * 8;
    int h0 = og * 2;
    int n0 = (tid >> 4) * 4;
    int wp0 = o0 + 4 * (o0 >> 5);

    float acc[4][8];
    #pragma unroll
    for (int oj = 0; oj < 8; ++oj) {
        float b = bg[(oj & 3) * 32 + h0 + (oj >> 2)];
        #pragma unroll
        for (int nj = 0; nj < 4; ++nj) acc[nj][oj] = b;
    }

    // chunk 0: x-terms (40 rows = 5 k x 8 ch)
    for (int i = tid; i < 40 * 128; i += 256) {
        int ci = i >> 7, o = i & 127;
        int k = ci >> 3, c = ci & 7, h = o >> 2, g = o & 3;
        Ws[ci * WSLD + o + 4 * (o >> 5)] = Wx[(((g * KCH + k) * 8) + c) * 32 + h];
    }
    for (int i = tid; i < NB * 5; i += 256) {
        int nl = i / 5, k = i % 5;
        int node = base + nl; if (node >= N) node = N - 1;
        const __half* sp = (k == 0) ? (xb + (size_t)node * 64 + t * 8)
                                    : (TXB + ((size_t)(k - 1) * N + node) * 64 + t * 8);
        float4 raw = *(const float4*)sp;
        const __half2* h = (const __half2*)&raw;
        float2 f0 = __half22float2(h[0]);
        float2 f1 = __half22float2(h[1]);
        float2 f2 = __half22float2(h[2]);
        float2 f3 = __half22float2(h[3]);
        int row = k * 8;
        Ts[(row + 0) * TSLD + nl] = f0.x; Ts[(row + 1) * TSLD + nl] = f0.y;
        Ts[(row + 2) * TSLD + nl] = f1.x; Ts[(row + 3) * TSLD + nl] = f1.y;
        Ts[(row + 4) * TSLD + nl] = f2.x; Ts[(row + 5) * TSLD + nl] = f2.y;
        Ts[(row + 6) * TSLD + nl] = f3.x; Ts[(row + 7) * TSLD + nl] = f3.y;
    }
    __syncthreads();
    #pragma unroll 4
    for (int c = 0; c < 40; ++c) {
        float4 wA = *(const float4*)(Ws + c * WSLD + wp0);
        float4 wB = *(const float4*)(Ws + c * WSLD + wp0 + 4);
        float4 tA = *(const float4*)(Ts + c * TSLD + n0);
        float wv[8] = {wA.x, wA.y, wA.z, wA.w, wB.x, wB.y, wB.z, wB.w};
        float tv[4] = {tA.x, tA.y, tA.z, tA.w};
        #pragma unroll
        for (int nj = 0; nj < 4; ++nj)
            #pragma unroll
            for (int oj = 0; oj < 8; ++oj)
                acc[nj][oj] += tv[nj] * wv[oj];
    }

    // chunks 1..5: H-terms k=0..4 (skipped at t=0, H0 = 0)
    if (withH) {
        for (int k = 0; k < KCH; ++k) {
            __syncthreads();
            for (int i = tid; i < 32 * 128; i += 256) {
                int ci = i >> 7, o = i & 127;
                int h = o >> 2, g = o & 3;
                Ws[ci * WSLD + o + 4 * (o >> 5)] = Wh[(((g * KCH + k) * 32) + ci) * 32 + h];
            }
            for (int i = tid; i < NB * 4; i += 256) {
                int nl = i >> 2, qq = i & 3;
                int node = base + nl; if (node >= N) node = N - 1;
                float4 raw = *(const float4*)(THall + ((size_t)k * N + node) * 32 + qq * 8);
                const __half2* h = (const __half2*)&raw;
                float2 f0 = __half22float2(h[0]);
                float2 f1 = __half22float2(h[1]);
                float2 f2 = __half22float2(h[2]);
                float2 f3 = __half22float2(h[3]);
                int row = qq * 8;
                Ts[(row + 0) * TSLD + nl] = f0.x; Ts[(row + 1) * TSLD + nl] = f0.y;
                Ts[(row + 2) * TSLD + nl] = f1.x; Ts[(row + 3) * TSLD + nl] = f1.y;
                Ts[(row + 4) * TSLD + nl] = f2.x; Ts[(row + 5) * TSLD + nl] = f2.y;
                Ts[(row + 6) * TSLD + nl] = f3.x; Ts[(row + 7) * TSLD + nl] = f3.y;
            }
            __syncthreads();
            #pragma unroll 4
            for (int c = 0; c < 32; ++c) {
                float4 wA = *(const float4*)(Ws + c * WSLD + wp0);
                float4 wB = *(const float4*)(Ws + c * WSLD + wp0 + 4);
                float4 tA = *(const float4*)(Ts + c * TSLD + n0);
                float wv[8] = {wA.x, wA.y, wA.z, wA.w, wB.x, wB.y, wB.z, wB.w};
                float tv[4] = {tA.x, tA.y, tA.z, tA.w};
                #pragma unroll
                for (int nj = 0; nj < 4; ++nj)
                    #pragma unroll
                    for (int oj = 0; oj < 8; ++oj)
                        acc[nj][oj] += tv[nj] * wv[oj];
            }
        }
    }

    // LSTM pointwise, register-local
    float wci0 = w_c[h0],      wci1 = w_c[h0 + 1];
    float wcf0 = w_c[32 + h0], wcf1 = w_c[32 + h0 + 1];
    float wco0 = w_c[64 + h0], wco1 = w_c[64 + h0 + 1];
    float hn_store[4][2];
    #pragma unroll
    for (int nj = 0; nj < 4; ++nj) {
        int node = base + n0 + nj;
        if (node < N) {
            size_t idx = (size_t)node * 32 + h0;
            float2 Co = *(const float2*)(Cst + idx);
            float2 Cn2, Hn;
            {
                float I  = sigmoidf_(acc[nj][0] + wci0 * Co.x);
                float F  = sigmoidf_(acc[nj][1] + wcf0 * Co.x);
                float Tg = tanhf_(acc[nj][2]);
                float Cn = F * Co.x + I * Tg;
                float O  = sigmoidf_(acc[nj][3] + wco0 * Cn);
                Cn2.x = Cn; Hn.x = O * tanhf_(Cn);
            }
            {
                float I  = sigmoidf_(acc[nj][4] + wci1 * Co.y);
                float F  = sigmoidf_(acc[nj][5] + wcf1 * Co.y);
                float Tg = tanhf_(acc[nj][6]);
                float Cn = F * Co.y + I * Tg;
                float O  = sigmoidf_(acc[nj][7] + wco1 * Cn);
                Cn2.y = Cn; Hn.y = O * tanhf_(Cn);
            }
            *(float2*)(Cst + idx) = Cn2;
            *(__half2*)(THall + idx) = __float22half2_rn(make_float2(Hn.x, Hn.y));
            hn_store[nj][0] = Hn.x; hn_store[nj][1] = Hn.y;
        } else {
            hn_store[nj][0] = 0.f; hn_store[nj][1] = 0.f;
        }
    }

    // fused output head (last timestep)
    if (doOut) {
        __syncthreads();
        #pragma unroll
        for (int nj = 0; nj < 4; ++nj) {
            Ts[(n0 + nj) * 33 + h0]     = fmaxf(hn_store[nj][0], 0.f);
            Ts[(n0 + nj) * 33 + h0 + 1] = fmaxf(hn_store[nj][1], 0.f);
        }
        __syncthreads();
        int nl = tid >> 2;
        int pp = (tid & 3) * 2;
        int node = base + nl;
        if (node < N) {
            float acc0 = b_lin[pp], acc1 = b_lin[pp + 1];
            const float* hp = Ts + nl * 33;
            #pragma unroll
            for (int h = 0; h < HID; ++h) {
                float hv = hp[h];
                acc0 += hv * W_lin[pp * HID + h];
                acc1 += hv * W_lin[(pp + 1) * HID + h];
            }
            float* op = out + (size_t)perm[node] * PERIODS + pp;
            op[0] = acc0; op[1] = acc1;
        }
    }
}

// ---------------- launch ----------------

extern "C" void kernel_launch(void* const* d_in, const int* in_sizes, int n_in,
                              void* d_out, int out_size, void* d_ws, size_t ws_size,
                              hipStream_t stream) {
    const float* xall  = (const float*)d_in[0];
    const int*   ei    = (const int*)d_in[1];
    const float* Wx    = (const float*)d_in[2];
    const float* Wh    = (const float*)d_in[3];
    const float* w_c   = (const float*)d_in[4];
    const float* bg    = (const float*)d_in[5];
    const float* W_lin = (const float*)d_in[6];
    const float* b_lin = (const float*)d_in[7];
    float* out = (float*)d_out;

    const int E = in_sizes[1] / 2;
    const int N = in_sizes[0] / (T_STEPS * F_IN);
    const int NT = (N + 255) / 256;
    const int* src = ei;
    const int* dst = ei + E;

    char* p = (char*)d_ws;
    auto carve = [&](size_t bytes) -> void* {
        void* r = (void*)p;
        p += (bytes + 255) & ~(size_t)255;
        return r;
    };
    // zero block: degi, cnt, fill, bar, Cst, THall slice 0 (= H0)
    char* zero_begin = p;
    int*    degi  = (int*)   carve((size_t)N * 4);
    int*    cnt   = (int*)   carve((size_t)N * 4);
    int*    fill  = (int*)   carve((size_t)N * 4);
    int*    bar   = (int*)   carve(512 * 4);
    float*  Cst   = (float*) carve((size_t)N * HID * 4);
    __half* THall = (__half*)carve((size_t)KCH * N * HID * 2);
    size_t zero_bytes = (size_t)((char*)THall - zero_begin) + (size_t)N * HID * 2;
    int*    hist     = (int*)   carve((size_t)256 * NT * 4);
    int*    histbase = (int*)   carve(((size_t)256 * NT + 1) * 4);
    float*  dis      = (float*) carve((size_t)N * 4);
    int*    perm     = (int*)   carve((size_t)N * 4);
    int*    iperm    = (int*)   carve((size_t)N * 4);
    int*    cntp     = (int*)   carve((size_t)N * 4);
    int*    rowptr   = (int*)   carve((size_t)(N + 1) * 4);
    int2*   cv       = (int2*)  carve((size_t)E * 8);
    __half* xb       = (__half*)carve((size_t)N * 64 * 2);
    __half* TXB      = (__half*)carve((size_t)4 * N * 64 * 2);

    hipMemsetAsync(zero_begin, 0, zero_bytes, stream);

    const int TB = 256;
    const int gE = (E + TB - 1) / TB;
    k_count<<<gE, TB, 0, stream>>>(src, dst, degi, cnt, E);
    k_hist2<<<NT, TB, 0, stream>>>(cnt, hist, N, NT);
    k_scan<<<1, 1024, 0, stream>>>(hist, histbase, 256 * NT);
    k_permscat2<<<NT, TB, 0, stream>>>(cnt, degi, histbase, perm, iperm, cntp, dis, N, NT);
    k_scan<<<1, 1024, 0, stream>>>(cntp, rowptr, N);
    k_scatxt<<<gE, TB, 0, stream>>>(src, dst, dis, rowptr, iperm, fill, cv, xall, xb, N, E);

    // x-phase Chebyshev chain: one kernel, 3 internal barriers (C = 64 halves)
    __half* TXB0 = TXB;
    __half* TXB1 = TXB + (size_t)N * 64;
    __half* TXB2 = TXB + (size_t)2 * N * 64;
    __half* TXB3 = TXB + (size_t)3 * N * 64;
    int bar_base = 0;
    k_lapquad<64><<<GB, TB, 0, stream>>>(xb, TXB0, TXB1, TXB2, TXB3,
                                         rowptr, cv, bar, bar_base, N);
    bar_base += 3;

    const int step_grid = (N + NB - 1) / NB;
    __half* TH0 = THall;
    __half* TH1 = THall + (size_t)N * HID;
    __half* TH2 = THall + (size_t)2 * N * HID;
    __half* TH3 = THall + (size_t)3 * N * HID;
    __half* TH4 = THall + (size_t)4 * N * HID;

    for (int t = 0; t < T_STEPS; ++t) {
        if (t > 0) {   // H-terms all zero at t=0 (H0 = 0): skip chain
            k_lapquad<HID><<<GB, TB, 0, stream>>>(TH0, TH1, TH2, TH3, TH4,
                                                  rowptr, cv, bar, bar_base, N);
            bar_base += 3;
        }
        k_step<<<step_grid, TB, 0, stream>>>(xb, TXB, THall, Cst, Wx, Wh, w_c, bg,
                                             W_lin, b_lin, perm, out,
                                             t, (t > 0) ? 1 : 0,
                                             (t == T_STEPS - 1) ? 1 : 0, N);
    }
}

// Round 11
// 658.546 us; speedup vs baseline: 3.0612x; 3.0612x over previous
//
#include <hip/hip_runtime.h>
#include <hip/hip_fp16.h>
#include <math.h>

#define T_STEPS 8
#define F_IN    8
#define HID     32
#define KCH     5
#define PERIODS 8
#define NB      64
#define WSLD    140
#define TSLD    68

typedef __attribute__((ext_vector_type(8))) _Float16 half8_t;
typedef __attribute__((ext_vector_type(4))) float    f32x4_t;

__device__ __forceinline__ float sigmoidf_(float x) { return 1.f / (1.f + __expf(-x)); }
__device__ __forceinline__ float tanhf_(float x) {
    float e = __expf(2.f * x);
    return 1.f - 2.f / (e + 1.f);
}

// ---------------- graph setup ----------------

__global__ void k_count(const int* __restrict__ src, const int* __restrict__ dst,
                        int* __restrict__ degi, int* __restrict__ cnt, int E) {
    int e = blockIdx.x * blockDim.x + threadIdx.x;
    if (e >= E) return;
    int s = src[e], d = dst[e];
    if (s != d) {
        atomicAdd(&degi[s], 1);
        atomicAdd(&cnt[d], 1);
    }
}

__global__ void k_hist2(const int* __restrict__ cnt, int* __restrict__ hist,
                        int N, int NT) {
    __shared__ int h[256];
    int tid = threadIdx.x, blk = blockIdx.x;
    h[tid] = 0;
    __syncthreads();
    int n = blk * 256 + tid;
    if (n < N) atomicAdd(&h[min(cnt[n], 255)], 1);
    __syncthreads();
    hist[tid * NT + blk] = h[tid];
}

// exclusive scan, single block 1024 threads, 32 elems/thread; valid n <= 32768
__global__ void __launch_bounds__(1024) k_scan(const int* __restrict__ in,
                                               int* __restrict__ outp, int n) {
    __shared__ int wsum[16];
    int tid = threadIdx.x;
    int base = tid * 32;
    int v[32];
    int s = 0;
    #pragma unroll
    for (int i = 0; i < 32; ++i) {
        int idx = base + i;
        int t = (idx < n) ? in[idx] : 0;
        v[i] = t; s += t;
    }
    int lane = tid & 63, wave = tid >> 6;
    int incl = s;
    #pragma unroll
    for (int off = 1; off < 64; off <<= 1) {
        int t = __shfl_up(incl, off, 64);
        if (lane >= off) incl += t;
    }
    if (lane == 63) wsum[wave] = incl;
    __syncthreads();
    if (tid < 64) {
        int w = (tid < 16) ? wsum[tid] : 0;
        int iw = w;
        #pragma unroll
        for (int off = 1; off < 16; off <<= 1) {
            int t = __shfl_up(iw, off, 64);
            if (tid >= off) iw += t;
        }
        if (tid < 16) wsum[tid] = iw - w;
    }
    __syncthreads();
    int excl = wsum[wave] + (incl - s);
    #pragma unroll
    for (int i = 0; i < 32; ++i) {
        int idx = base + i;
        if (idx < n) outp[idx] = excl;
        excl += v[i];
    }
    if (tid == 1023) outp[n] = wsum[15] + incl;
}

__global__ void k_permscat2(const int* __restrict__ cnt, const int* __restrict__ degi,
                            const int* __restrict__ histbase,
                            int* __restrict__ perm, int* __restrict__ iperm,
                            int* __restrict__ cntp, float* __restrict__ dis,
                            int N, int NT) {
    __shared__ int key[256];
    int tid = threadIdx.x, blk = blockIdx.x;
    int n = blk * 256 + tid;
    int k = (n < N) ? min(cnt[n], 255) : -1;
    key[tid] = k;
    __syncthreads();
    if (n < N) {
        int r = 0;
        for (int j = 0; j < tid; ++j) r += (key[j] == k);
        int pos = histbase[k * NT + blk] + r;
        perm[pos] = n;
        iperm[n] = pos;
        cntp[pos] = cnt[n];
        int dg = degi[n];
        dis[n] = (dg > 0) ? rsqrtf((float)dg) : 0.f;
    }
}

__global__ void k_scatxt(const int* __restrict__ src, const int* __restrict__ dst,
                         const float* __restrict__ dis, const int* __restrict__ rowptr,
                         const int* __restrict__ iperm, int* __restrict__ fill,
                         int2* __restrict__ cv, const float* __restrict__ xall,
                         __half* __restrict__ xb, int N, int E) {
    int gsz = (int)(gridDim.x * blockDim.x);
    int gtid = blockIdx.x * blockDim.x + threadIdx.x;
    for (int e = gtid; e < E; e += gsz) {
        int s = src[e], d = dst[e];
        if (s != d) {
            float nv = -dis[s] * dis[d];
            int dp = iperm[d];
            int p = atomicAdd(&fill[dp], 1);
            cv[rowptr[dp] + p] = make_int2(iperm[s], __float_as_int(nv));
        }
    }
    for (int i = gtid; i < N * T_STEPS; i += gsz) {
        int n = i >> 3, t = i & 7;
        float4 a = *(const float4*)(xall + ((size_t)t * N + n) * 8);
        float4 b = *(const float4*)(xall + ((size_t)t * N + n) * 8 + 4);
        __half2 h[4];
        h[0] = __float22half2_rn(make_float2(a.x, a.y));
        h[1] = __float22half2_rn(make_float2(a.z, a.w));
        h[2] = __float22half2_rn(make_float2(b.x, b.y));
        h[3] = __float22half2_rn(make_float2(b.z, b.w));
        *(float4*)(xb + (size_t)iperm[n] * 64 + t * 8) = *(float4*)h;
    }
}

// pre-pack Wh into fp16 MFMA B-fragments: Bpack[k][nt][lane][j]
// = Wh[g][k][kk=quad*8+j][h], o = nt*16 + (lane&15) = g*32+h  (m97 B^T pattern)
__global__ void k_wprep(const float* __restrict__ Wh, __half* __restrict__ Bpack) {
    int idx = blockIdx.x * blockDim.x + threadIdx.x;
    if (idx >= KCH * 8 * 64 * 8) return;
    int j = idx & 7;
    int lane = (idx >> 3) & 63;
    int nt = (idx >> 9) & 7;
    int k = idx >> 12;
    int col = lane & 15, quad = lane >> 4;
    int kk = quad * 8 + j;
    int o = nt * 16 + col;
    int g = o >> 5, h = o & 31;
    Bpack[idx] = __float2half(Wh[(((g * KCH + k) * 32) + kk) * 32 + h]);
}

// ---------------- Laplacian: pull CSR, fp16 features, ES-way edge split -----
// cv loads are NON-TEMPORAL: the edge stream (15 MB redundant reads) was
// thrashing the 4MB/XCD L2 and evicting the hot 1.9MB node rows (R10 FETCH data).
template <int C, int ES>
__global__ void __launch_bounds__(256) k_lap_h(__half* __restrict__ outp,
                                               const __half* __restrict__ xin,
                                               const __half* __restrict__ xprev,
                                               float alpha, float beta,
                                               const int* __restrict__ rowptr,
                                               const int2* __restrict__ cv, int N) {
    constexpr int Q = C / 8;
    constexpr int W = Q * ES;
    int idx = blockIdx.x * 256 + threadIdx.x;
    int node = idx / W;
    int r = idx % W;
    int q = r % Q, s = r / Q;
    if (node >= N) return;
    int beg = rowptr[node], end = rowptr[node + 1];
    const long long* cvll = (const long long*)cv;
    float a0 = 0.f, a1 = 0.f, a2 = 0.f, a3 = 0.f, a4 = 0.f, a5 = 0.f, a6 = 0.f, a7 = 0.f;
    #pragma unroll 4
    for (int j = beg + s; j < end; j += ES) {
        long long pv = __builtin_nontemporal_load(cvll + j);
        int pcol = (int)(unsigned int)(pv & 0xffffffffLL);
        float nv = __int_as_float((int)(pv >> 32));
        float4 raw = *(const float4*)(xin + (size_t)pcol * C + q * 8);
        const __half2* h = (const __half2*)&raw;
        float2 f0 = __half22float2(h[0]);
        float2 f1 = __half22float2(h[1]);
        float2 f2 = __half22float2(h[2]);
        float2 f3 = __half22float2(h[3]);
        a0 += nv * f0.x; a1 += nv * f0.y; a2 += nv * f1.x; a3 += nv * f1.y;
        a4 += nv * f2.x; a5 += nv * f2.y; a6 += nv * f3.x; a7 += nv * f3.y;
    }
    #pragma unroll
    for (int m = Q; m < W; m <<= 1) {
        a0 += __shfl_xor(a0, m, 64); a1 += __shfl_xor(a1, m, 64);
        a2 += __shfl_xor(a2, m, 64); a3 += __shfl_xor(a3, m, 64);
        a4 += __shfl_xor(a4, m, 64); a5 += __shfl_xor(a5, m, 64);
        a6 += __shfl_xor(a6, m, 64); a7 += __shfl_xor(a7, m, 64);
    }
    if (s != 0) return;
    size_t off = (size_t)node * C + q * 8;
    float r0 = alpha * a0, r1 = alpha * a1, r2 = alpha * a2, r3 = alpha * a3;
    float r4 = alpha * a4, r5 = alpha * a5, r6 = alpha * a6, r7 = alpha * a7;
    if (beta != 0.f) {
        float4 raw = *(const float4*)(xprev + off);
        const __half2* h = (const __half2*)&raw;
        float2 f0 = __half22float2(h[0]);
        float2 f1 = __half22float2(h[1]);
        float2 f2 = __half22float2(h[2]);
        float2 f3 = __half22float2(h[3]);
        r0 += beta * f0.x; r1 += beta * f0.y; r2 += beta * f1.x; r3 += beta * f1.y;
        r4 += beta * f2.x; r5 += beta * f2.y; r6 += beta * f3.x; r7 += beta * f3.y;
    }
    __half2 o[4];
    o[0] = __float22half2_rn(make_float2(r0, r1));
    o[1] = __float22half2_rn(make_float2(r2, r3));
    o[2] = __float22half2_rn(make_float2(r4, r5));
    o[3] = __float22half2_rn(make_float2(r6, r7));
    *(float4*)(outp + off) = *(float4*)o;
}

// ---------------- Gx precompute: x-contribution + bias for ALL timesteps -----
// Gx[t][n][o] (fp16, natural o = g*32+h) = bg[o] + sum_{k,c} TXk[n][t*8+c] * Wx[g][k][c][h]
__global__ void __launch_bounds__(256) k_gx(
    const __half* __restrict__ xb, const __half* __restrict__ TXB,
    const float* __restrict__ Wx, const float* __restrict__ bg,
    __half* __restrict__ Gx, int N) {
    __shared__ float Ws[40 * WSLD];
    __shared__ float Ts[40 * TSLD];
    int tid = threadIdx.x;
    int base = blockIdx.x * NB;
    int t = blockIdx.y;
    int o0 = (tid & 15) * 8;
    int n0 = (tid >> 4) * 4;
    int wp0 = o0 + 4 * (o0 >> 5);

    for (int i = tid; i < 40 * 128; i += 256) {
        int ci = i >> 7, o = i & 127;
        int k = ci >> 3, c = ci & 7, g = o >> 5, h = o & 31;
        Ws[ci * WSLD + o + 4 * (o >> 5)] = Wx[(((g * KCH + k) * 8) + c) * 32 + h];
    }
    for (int i = tid; i < NB * 5; i += 256) {
        int nl = i / 5, k = i % 5;
        int node = base + nl; if (node >= N) node = N - 1;
        const __half* sp = (k == 0) ? (xb + (size_t)node * 64 + t * 8)
                                    : (TXB + ((size_t)(k - 1) * N + node) * 64 + t * 8);
        float4 raw = *(const float4*)sp;
        const __half2* h = (const __half2*)&raw;
        float2 f0 = __half22float2(h[0]);
        float2 f1 = __half22float2(h[1]);
        float2 f2 = __half22float2(h[2]);
        float2 f3 = __half22float2(h[3]);
        int row = k * 8;
        Ts[(row + 0) * TSLD + nl] = f0.x; Ts[(row + 1) * TSLD + nl] = f0.y;
        Ts[(row + 2) * TSLD + nl] = f1.x; Ts[(row + 3) * TSLD + nl] = f1.y;
        Ts[(row + 4) * TSLD + nl] = f2.x; Ts[(row + 5) * TSLD + nl] = f2.y;
        Ts[(row + 6) * TSLD + nl] = f3.x; Ts[(row + 7) * TSLD + nl] = f3.y;
    }
    __syncthreads();

    float acc[4][8];
    #pragma unroll
    for (int oj = 0; oj < 8; ++oj) {
        float b = bg[o0 + oj];
        #pragma unroll
        for (int nj = 0; nj < 4; ++nj) acc[nj][oj] = b;
    }
    #pragma unroll 4
    for (int c = 0; c < 40; ++c) {
        float4 wA = *(const float4*)(Ws + c * WSLD + wp0);
        float4 wB = *(const float4*)(Ws + c * WSLD + wp0 + 4);
        float4 tA = *(const float4*)(Ts + c * TSLD + n0);
        float wv[8] = {wA.x, wA.y, wA.z, wA.w, wB.x, wB.y, wB.z, wB.w};
        float tv[4] = {tA.x, tA.y, tA.z, tA.w};
        #pragma unroll
        for (int nj = 0; nj < 4; ++nj)
            #pragma unroll
            for (int oj = 0; oj < 8; ++oj)
                acc[nj][oj] += tv[nj] * wv[oj];
    }
    #pragma unroll
    for (int nj = 0; nj < 4; ++nj) {
        int node = base + n0 + nj;
        if (node < N) {
            float4 pack;
            __half2* hp = (__half2*)&pack;
            hp[0] = __float22half2_rn(make_float2(acc[nj][0], acc[nj][1]));
            hp[1] = __float22half2_rn(make_float2(acc[nj][2], acc[nj][3]));
            hp[2] = __float22half2_rn(make_float2(acc[nj][4], acc[nj][5]));
            hp[3] = __float22half2_rn(make_float2(acc[nj][6], acc[nj][7]));
            *(float4*)(Gx + ((size_t)t * N + node) * 128 + o0) = pack;
        }
    }
}

// ---------------- t=0 step: pointwise only (H0 = C0 = 0) ----------------
__global__ void k_step0(const __half* __restrict__ Gx, const float* __restrict__ w_c,
                        float* __restrict__ Cst, __half* __restrict__ H, int N) {
    int idx = blockIdx.x * blockDim.x + threadIdx.x;
    if (idx >= N * HID) return;
    int node = idx >> 5, h = idx & 31;
    const __half* g = Gx + (size_t)node * 128;
    float I  = sigmoidf_(__half2float(g[h]));
    float Tg = tanhf_(__half2float(g[64 + h]));
    float Cn = I * Tg;
    float O  = sigmoidf_(__half2float(g[96 + h]) + w_c[64 + h] * Cn);
    Cst[idx] = Cn;
    H[idx] = __float2half(O * tanhf_(Cn));
}

// ---------------- MFMA step: H-gate GEMM + LSTM (+ output head at t=T-1) ----
// M=64 nodes, N=128 gates, K=160 (5 Cheb terms x 32). 4 waves: wave = M-tile.
// A loaded direct from fp16 TH rows (A[m=lane&15][k=quad*8+j], 16B/lane/chunk).
// C layout: n = nt*16+(lane&15), m = quad*4+reg  ->  lane owns all 4 gates of
// h = col and h = col+16 (nt = 2g+b) for its 4 nodes: register-local LSTM.
__global__ void __launch_bounds__(256) k_stepM(
    const __half* __restrict__ Gx, __half* __restrict__ THall,
    float* __restrict__ Cst, const __half* __restrict__ Bpack,
    const float* __restrict__ w_c,
    const float* __restrict__ W_lin, const float* __restrict__ b_lin,
    const int* __restrict__ perm, float* __restrict__ out,
    int t, int doOut, int N) {
    __shared__ float Hbuf[64 * 33];
    int tid = threadIdx.x;
    int wave = tid >> 6, lane = tid & 63;
    int col = lane & 15, quad = lane >> 4;
    int base = blockIdx.x * NB;
    int node_a = base + wave * 16 + col; if (node_a >= N) node_a = N - 1;
    int nc0 = base + wave * 16 + quad * 4;

    f32x4_t acc[8];
    #pragma unroll
    for (int nt = 0; nt < 8; ++nt) {
        #pragma unroll
        for (int reg = 0; reg < 4; ++reg) {
            int nc = nc0 + reg; if (nc >= N) nc = N - 1;
            acc[nt][reg] = __half2float(Gx[((size_t)t * N + nc) * 128 + nt * 16 + col]);
        }
    }

    const half8_t* Bp = (const half8_t*)Bpack;
    #pragma unroll
    for (int k = 0; k < KCH; ++k) {
        half8_t a = *(const half8_t*)(THall + ((size_t)k * N + node_a) * 32 + quad * 8);
        #pragma unroll
        for (int nt = 0; nt < 8; ++nt) {
            half8_t b = Bp[(k * 8 + nt) * 64 + lane];
            acc[nt] = __builtin_amdgcn_mfma_f32_16x16x32_f16(a, b, acc[nt], 0, 0, 0);
        }
    }

    #pragma unroll
    for (int reg = 0; reg < 4; ++reg) {
        int node = nc0 + reg;
        if (node < N) {
            #pragma unroll
            for (int b = 0; b < 2; ++b) {
                int h = col + 16 * b;
                size_t idx = (size_t)node * 32 + h;
                float Co = Cst[idx];
                float I  = sigmoidf_(acc[0 + b][reg] + w_c[h] * Co);
                float F  = sigmoidf_(acc[2 + b][reg] + w_c[32 + h] * Co);
                float Tg = tanhf_(acc[4 + b][reg]);
                float Cn = F * Co + I * Tg;
                float O  = sigmoidf_(acc[6 + b][reg] + w_c[64 + h] * Cn);
                float Hn = O * tanhf_(Cn);
                Cst[idx] = Cn;
                THall[idx] = __float2half(Hn);
                if (doOut) Hbuf[(wave * 16 + quad * 4 + reg) * 33 + h] = fmaxf(Hn, 0.f);
            }
        } else if (doOut) {
            Hbuf[(wave * 16 + quad * 4 + reg) * 33 + col] = 0.f;
            Hbuf[(wave * 16 + quad * 4 + reg) * 33 + col + 16] = 0.f;
        }
    }

    if (doOut) {
        __syncthreads();
        int nl = tid >> 2, pp = (tid & 3) * 2;
        int node = base + nl;
        if (node < N) {
            float a0 = b_lin[pp], a1 = b_lin[pp + 1];
            const float* hp = Hbuf + nl * 33;
            #pragma unroll
            for (int h = 0; h < HID; ++h) {
                float hv = hp[h];
                a0 += hv * W_lin[pp * HID + h];
                a1 += hv * W_lin[(pp + 1) * HID + h];
            }
            float* op = out + (size_t)perm[node] * PERIODS + pp;
            op[0] = a0; op[1] = a1;
        }
    }
}

// ---------------- launch ----------------

extern "C" void kernel_launch(void* const* d_in, const int* in_sizes, int n_in,
                              void* d_out, int out_size, void* d_ws, size_t ws_size,
                              hipStream_t stream) {
    const float* xall  = (const float*)d_in[0];
    const int*   ei    = (const int*)d_in[1];
    const float* Wx    = (const float*)d_in[2];
    const float* Wh    = (const float*)d_in[3];
    const float* w_c   = (const float*)d_in[4];
    const float* bg    = (const float*)d_in[5];
    const float* W_lin = (const float*)d_in[6];
    const float* b_lin = (const float*)d_in[7];
    float* out = (float*)d_out;

    const int E = in_sizes[1] / 2;
    const int N = in_sizes[0] / (T_STEPS * F_IN);
    const int NT = (N + 255) / 256;
    const int* src = ei;
    const int* dst = ei + E;

    char* p = (char*)d_ws;
    auto carve = [&](size_t bytes) -> void* {
        void* r = (void*)p;
        p += (bytes + 255) & ~(size_t)255;
        return r;
    };
    // zero block: degi, cnt, fill, Cst, THall slice 0 (= H0)
    char* zero_begin = p;
    int*    degi  = (int*)   carve((size_t)N * 4);
    int*    cnt   = (int*)   carve((size_t)N * 4);
    int*    fill  = (int*)   carve((size_t)N * 4);
    float*  Cst   = (float*) carve((size_t)N * HID * 4);
    __half* THall = (__half*)carve((size_t)KCH * N * HID * 2);
    size_t zero_bytes = (size_t)((char*)THall - zero_begin) + (size_t)N * HID * 2;
    int*    hist     = (int*)   carve((size_t)256 * NT * 4);
    int*    histbase = (int*)   carve(((size_t)256 * NT + 1) * 4);
    float*  dis      = (float*) carve((size_t)N * 4);
    int*    perm     = (int*)   carve((size_t)N * 4);
    int*    iperm    = (int*)   carve((size_t)N * 4);
    int*    cntp     = (int*)   carve((size_t)N * 4);
    int*    rowptr   = (int*)   carve((size_t)(N + 1) * 4);
    int2*   cv       = (int2*)  carve((size_t)E * 8);
    __half* xb       = (__half*)carve((size_t)N * 64 * 2);
    __half* TXB      = (__half*)carve((size_t)4 * N * 64 * 2);
    __half* Bpack    = (__half*)carve((size_t)KCH * 8 * 64 * 8 * 2);
    __half* Gx       = (__half*)carve((size_t)T_STEPS * N * 128 * 2);

    hipMemsetAsync(zero_begin, 0, zero_bytes, stream);

    const int TB = 256;
    const int gE = (E + TB - 1) / TB;
    k_wprep<<<(KCH * 8 * 64 * 8 + TB - 1) / TB, TB, 0, stream>>>(Wh, Bpack);
    k_count<<<gE, TB, 0, stream>>>(src, dst, degi, cnt, E);
    k_hist2<<<NT, TB, 0, stream>>>(cnt, hist, N, NT);
    k_scan<<<1, 1024, 0, stream>>>(hist, histbase, 256 * NT);
    k_permscat2<<<NT, TB, 0, stream>>>(cnt, degi, histbase, perm, iperm, cntp, dis, N, NT);
    k_scan<<<1, 1024, 0, stream>>>(cntp, rowptr, N);
    k_scatxt<<<gE, TB, 0, stream>>>(src, dst, dis, rowptr, iperm, fill, cv, xall, xb, N, E);

    // batched x-phase Chebyshev terms over all timesteps (C = 64 halves, ES=4)
    __half* TXB0 = TXB;
    __half* TXB1 = TXB + (size_t)N * 64;
    __half* TXB2 = TXB + (size_t)2 * N * 64;
    __half* TXB3 = TXB + (size_t)3 * N * 64;
    const int lapx_grid = (N * 32 + TB - 1) / TB;   // W = 32 lanes/node
    k_lap_h<64, 4><<<lapx_grid, TB, 0, stream>>>(TXB0, xb,   nullptr, 1.f,  0.f, rowptr, cv, N);
    k_lap_h<64, 4><<<lapx_grid, TB, 0, stream>>>(TXB1, TXB0, xb,      2.f, -1.f, rowptr, cv, N);
    k_lap_h<64, 4><<<lapx_grid, TB, 0, stream>>>(TXB2, TXB1, TXB0,    2.f, -1.f, rowptr, cv, N);
    k_lap_h<64, 4><<<lapx_grid, TB, 0, stream>>>(TXB3, TXB2, TXB1,    2.f, -1.f, rowptr, cv, N);

    // x-gate contributions (+bias) for all 8 timesteps, fp16
    const int step_grid = (N + NB - 1) / NB;
    k_gx<<<dim3(step_grid, T_STEPS), TB, 0, stream>>>(xb, TXB, Wx, bg, Gx, N);

    const int laph_grid = (N * 16 + TB - 1) / TB;   // W = 16 lanes/node
    __half* TH0 = THall;
    __half* TH1 = THall + (size_t)N * HID;
    __half* TH2 = THall + (size_t)2 * N * HID;
    __half* TH3 = THall + (size_t)3 * N * HID;
    __half* TH4 = THall + (size_t)4 * N * HID;

    // t = 0: H0 = C0 = 0 -> pointwise only
    k_step0<<<(N * HID + TB - 1) / TB, TB, 0, stream>>>(Gx, w_c, Cst, TH0, N);

    for (int t = 1; t < T_STEPS; ++t) {
        k_lap_h<HID, 4><<<laph_grid, TB, 0, stream>>>(TH1, TH0, nullptr, 1.f,  0.f, rowptr, cv, N);
        k_lap_h<HID, 4><<<laph_grid, TB, 0, stream>>>(TH2, TH1, TH0,     2.f, -1.f, rowptr, cv, N);
        k_lap_h<HID, 4><<<laph_grid, TB, 0, stream>>>(TH3, TH2, TH1,     2.f, -1.f, rowptr, cv, N);
        k_lap_h<HID, 4><<<laph_grid, TB, 0, stream>>>(TH4, TH3, TH2,     2.f, -1.f, rowptr, cv, N);
        k_stepM<<<step_grid, TB, 0, stream>>>(Gx, THall, Cst, Bpack, w_c,
                                              W_lin, b_lin, perm, out,
                                              t, (t == T_STEPS - 1) ? 1 : 0, N);
    }
}

// Round 12
// 631.679 us; speedup vs baseline: 3.1914x; 1.0425x over previous
//
#include <hip/hip_runtime.h>
#include <hip/hip_fp16.h>
#include <math.h>

#define T_STEPS 8
#define F_IN    8
#define HID     32
#define KCH     5
#define PERIODS 8
#define NB      64

typedef __attribute__((ext_vector_type(8))) _Float16 half8_t;
typedef __attribute__((ext_vector_type(4))) float    f32x4_t;

__device__ __forceinline__ float sigmoidf_(float x) { return 1.f / (1.f + __expf(-x)); }
__device__ __forceinline__ float tanhf_(float x) {
    float e = __expf(2.f * x);
    return 1.f - 2.f / (e + 1.f);
}

// ---------------- graph setup ----------------

__global__ void k_count(const int* __restrict__ src, const int* __restrict__ dst,
                        int* __restrict__ degi, int* __restrict__ cnt, int E) {
    int e = blockIdx.x * blockDim.x + threadIdx.x;
    if (e >= E) return;
    int s = src[e], d = dst[e];
    if (s != d) {
        atomicAdd(&degi[s], 1);
        atomicAdd(&cnt[d], 1);
    }
}

__global__ void k_hist2(const int* __restrict__ cnt, int* __restrict__ hist,
                        int N, int NT) {
    __shared__ int h[256];
    int tid = threadIdx.x, blk = blockIdx.x;
    h[tid] = 0;
    __syncthreads();
    int n = blk * 256 + tid;
    if (n < N) atomicAdd(&h[min(cnt[n], 255)], 1);
    __syncthreads();
    hist[tid * NT + blk] = h[tid];
}

// exclusive scan, single block 1024 threads, 32 elems/thread; valid n <= 32768
__global__ void __launch_bounds__(1024) k_scan(const int* __restrict__ in,
                                               int* __restrict__ outp, int n) {
    __shared__ int wsum[16];
    int tid = threadIdx.x;
    int base = tid * 32;
    int v[32];
    int s = 0;
    #pragma unroll
    for (int i = 0; i < 32; ++i) {
        int idx = base + i;
        int t = (idx < n) ? in[idx] : 0;
        v[i] = t; s += t;
    }
    int lane = tid & 63, wave = tid >> 6;
    int incl = s;
    #pragma unroll
    for (int off = 1; off < 64; off <<= 1) {
        int t = __shfl_up(incl, off, 64);
        if (lane >= off) incl += t;
    }
    if (lane == 63) wsum[wave] = incl;
    __syncthreads();
    if (tid < 64) {
        int w = (tid < 16) ? wsum[tid] : 0;
        int iw = w;
        #pragma unroll
        for (int off = 1; off < 16; off <<= 1) {
            int t = __shfl_up(iw, off, 64);
            if (tid >= off) iw += t;
        }
        if (tid < 16) wsum[tid] = iw - w;
    }
    __syncthreads();
    int excl = wsum[wave] + (incl - s);
    #pragma unroll
    for (int i = 0; i < 32; ++i) {
        int idx = base + i;
        if (idx < n) outp[idx] = excl;
        excl += v[i];
    }
    if (tid == 1023) outp[n] = wsum[15] + incl;
}

__global__ void k_permscat2(const int* __restrict__ cnt, const int* __restrict__ degi,
                            const int* __restrict__ histbase,
                            int* __restrict__ perm, int* __restrict__ iperm,
                            int* __restrict__ cntp, float* __restrict__ dis,
                            int N, int NT) {
    __shared__ int key[256];
    int tid = threadIdx.x, blk = blockIdx.x;
    int n = blk * 256 + tid;
    int k = (n < N) ? min(cnt[n], 255) : -1;
    key[tid] = k;
    __syncthreads();
    if (n < N) {
        int r = 0;
        for (int j = 0; j < tid; ++j) r += (key[j] == k);
        int pos = histbase[k * NT + blk] + r;
        perm[pos] = n;
        iperm[n] = pos;
        cntp[pos] = cnt[n];
        int dg = degi[n];
        dis[n] = (dg > 0) ? rsqrtf((float)dg) : 0.f;
    }
}

// merged: edge scatter + x transpose/permute/fp16 + MFMA B-fragment packing
// Bpack  (Wh): [k][nt][lane][j], kk = quad*8+j, o = nt*16+col = g*32+h
// Bxpack (Wx): [c][nt][lane][j], kk = c*32+quad*8+j (kcheb=kk>>3, ch=kk&7; >=5 -> 0)
__global__ void k_scatxt(const int* __restrict__ src, const int* __restrict__ dst,
                         const float* __restrict__ dis, const int* __restrict__ rowptr,
                         const int* __restrict__ iperm, int* __restrict__ fill,
                         int2* __restrict__ cv, const float* __restrict__ xall,
                         __half* __restrict__ xb,
                         const float* __restrict__ Wh, __half* __restrict__ Bpack,
                         const float* __restrict__ Wx, __half* __restrict__ Bxpack,
                         int N, int E) {
    int gsz = (int)(gridDim.x * blockDim.x);
    int gtid = blockIdx.x * blockDim.x + threadIdx.x;
    for (int e = gtid; e < E; e += gsz) {
        int s = src[e], d = dst[e];
        if (s != d) {
            float nv = -dis[s] * dis[d];
            int dp = iperm[d];
            int p = atomicAdd(&fill[dp], 1);
            cv[rowptr[dp] + p] = make_int2(iperm[s], __float_as_int(nv));
        }
    }
    for (int i = gtid; i < N * T_STEPS; i += gsz) {
        int n = i >> 3, t = i & 7;
        float4 a = *(const float4*)(xall + ((size_t)t * N + n) * 8);
        float4 b = *(const float4*)(xall + ((size_t)t * N + n) * 8 + 4);
        __half2 h[4];
        h[0] = __float22half2_rn(make_float2(a.x, a.y));
        h[1] = __float22half2_rn(make_float2(a.z, a.w));
        h[2] = __float22half2_rn(make_float2(b.x, b.y));
        h[3] = __float22half2_rn(make_float2(b.z, b.w));
        *(float4*)(xb + (size_t)iperm[n] * 64 + t * 8) = *(float4*)h;
    }
    for (int i = gtid; i < KCH * 8 * 64 * 8; i += gsz) {
        int j = i & 7, lane = (i >> 3) & 63, nt = (i >> 9) & 7, k = i >> 12;
        int col = lane & 15, quad = lane >> 4;
        int kk = quad * 8 + j;
        int o = nt * 16 + col, g = o >> 5, h = o & 31;
        Bpack[i] = __float2half(Wh[(((g * KCH + k) * 32) + kk) * 32 + h]);
    }
    for (int i = gtid; i < 2 * 8 * 64 * 8; i += gsz) {
        int j = i & 7, lane = (i >> 3) & 63, nt = (i >> 9) & 7, c = i >> 12;
        int col = lane & 15, quad = lane >> 4;
        int kk = c * 32 + quad * 8 + j;
        int kcheb = kk >> 3, ch = kk & 7;
        int o = nt * 16 + col, g = o >> 5, h = o & 31;
        float v = (kcheb < KCH) ? Wx[(((g * KCH + kcheb) * 8) + ch) * 32 + h] : 0.f;
        Bxpack[i] = __float2half(v);
    }
}

// ---------------- Laplacian: pull CSR, fp16 features, ES-way edge split -----
// cv loads NON-TEMPORAL (edge stream thrashes per-XCD L2 otherwise).
template <int C, int ES>
__global__ void __launch_bounds__(256) k_lap_h(__half* __restrict__ outp,
                                               const __half* __restrict__ xin,
                                               const __half* __restrict__ xprev,
                                               float alpha, float beta,
                                               const int* __restrict__ rowptr,
                                               const int2* __restrict__ cv, int N) {
    constexpr int Q = C / 8;
    constexpr int W = Q * ES;
    int idx = blockIdx.x * 256 + threadIdx.x;
    int node = idx / W;
    int r = idx % W;
    int q = r % Q, s = r / Q;
    if (node >= N) return;
    int beg = rowptr[node], end = rowptr[node + 1];
    const long long* cvll = (const long long*)cv;
    float a0 = 0.f, a1 = 0.f, a2 = 0.f, a3 = 0.f, a4 = 0.f, a5 = 0.f, a6 = 0.f, a7 = 0.f;
    #pragma unroll 4
    for (int j = beg + s; j < end; j += ES) {
        long long pv = __builtin_nontemporal_load(cvll + j);
        int pcol = (int)(unsigned int)(pv & 0xffffffffLL);
        float nv = __int_as_float((int)(pv >> 32));
        float4 raw = *(const float4*)(xin + (size_t)pcol * C + q * 8);
        const __half2* h = (const __half2*)&raw;
        float2 f0 = __half22float2(h[0]);
        float2 f1 = __half22float2(h[1]);
        float2 f2 = __half22float2(h[2]);
        float2 f3 = __half22float2(h[3]);
        a0 += nv * f0.x; a1 += nv * f0.y; a2 += nv * f1.x; a3 += nv * f1.y;
        a4 += nv * f2.x; a5 += nv * f2.y; a6 += nv * f3.x; a7 += nv * f3.y;
    }
    #pragma unroll
    for (int m = Q; m < W; m <<= 1) {
        a0 += __shfl_xor(a0, m, 64); a1 += __shfl_xor(a1, m, 64);
        a2 += __shfl_xor(a2, m, 64); a3 += __shfl_xor(a3, m, 64);
        a4 += __shfl_xor(a4, m, 64); a5 += __shfl_xor(a5, m, 64);
        a6 += __shfl_xor(a6, m, 64); a7 += __shfl_xor(a7, m, 64);
    }
    if (s != 0) return;
    size_t off = (size_t)node * C + q * 8;
    float r0 = alpha * a0, r1 = alpha * a1, r2 = alpha * a2, r3 = alpha * a3;
    float r4 = alpha * a4, r5 = alpha * a5, r6 = alpha * a6, r7 = alpha * a7;
    if (beta != 0.f) {
        float4 raw = *(const float4*)(xprev + off);
        const __half2* h = (const __half2*)&raw;
        float2 f0 = __half22float2(h[0]);
        float2 f1 = __half22float2(h[1]);
        float2 f2 = __half22float2(h[2]);
        float2 f3 = __half22float2(h[3]);
        r0 += beta * f0.x; r1 += beta * f0.y; r2 += beta * f1.x; r3 += beta * f1.y;
        r4 += beta * f2.x; r5 += beta * f2.y; r6 += beta * f3.x; r7 += beta * f3.y;
    }
    __half2 o[4];
    o[0] = __float22half2_rn(make_float2(r0, r1));
    o[1] = __float22half2_rn(make_float2(r2, r3));
    o[2] = __float22half2_rn(make_float2(r4, r5));
    o[3] = __float22half2_rn(make_float2(r6, r7));
    *(float4*)(outp + off) = *(float4*)o;
}

// ---------------- MFMA step: x-GEMM + H-GEMM + LSTM (+ output head) ---------
// M=64 nodes/block, N=128 gates. x-part: K=64 (40 real, zero-padded via A quads).
// H-part: K=160 (5 Cheb terms x 32), skipped at t=0 (H0=0).
// A direct from fp16 rows (A[m=lane&15][k=quad*8+j]); B pre-packed per-lane.
// C layout: o = nt*16+col (natural gate index), m = quad*4+reg -> lane owns all
// 4 gates of (node, h=col) and (node, h=col+16): register-local LSTM.
__global__ void __launch_bounds__(256) k_stepM(
    const __half* __restrict__ xb, const __half* __restrict__ TXB,
    __half* __restrict__ THall, float* __restrict__ Cst,
    const __half* __restrict__ Bpack, const __half* __restrict__ Bxpack,
    const float* __restrict__ w_c, const float* __restrict__ bg,
    const float* __restrict__ W_lin, const float* __restrict__ b_lin,
    const int* __restrict__ perm, float* __restrict__ out,
    int t, int withH, int doOut, int N) {
    __shared__ float Hbuf[64 * 33];
    int tid = threadIdx.x;
    int wave = tid >> 6, lane = tid & 63;
    int col = lane & 15, quad = lane >> 4;
    int base = blockIdx.x * NB;
    int node_a = base + wave * 16 + col; if (node_a >= N) node_a = N - 1;
    int nc0 = base + wave * 16 + quad * 4;

    f32x4_t acc[8];
    #pragma unroll
    for (int nt = 0; nt < 8; ++nt) {
        float b = bg[nt * 16 + col];
        acc[nt][0] = b; acc[nt][1] = b; acc[nt][2] = b; acc[nt][3] = b;
    }

    // ---- x-part: 2 K-chunks (kcheb = quad and 4+quad; quads >=5 are zero) ----
    const half8_t* Bx = (const half8_t*)Bxpack;
    {
        const __half* sp0 = (quad == 0)
            ? (xb + (size_t)node_a * 64 + t * 8)
            : (TXB + ((size_t)(quad - 1) * N + node_a) * 64 + t * 8);
        half8_t ax0 = *(const half8_t*)sp0;
        half8_t ax1 = {};
        if (quad == 0)
            ax1 = *(const half8_t*)(TXB + ((size_t)3 * N + node_a) * 64 + t * 8);
        #pragma unroll
        for (int nt = 0; nt < 8; ++nt)
            acc[nt] = __builtin_amdgcn_mfma_f32_16x16x32_f16(ax0, Bx[nt * 64 + lane], acc[nt], 0, 0, 0);
        #pragma unroll
        for (int nt = 0; nt < 8; ++nt)
            acc[nt] = __builtin_amdgcn_mfma_f32_16x16x32_f16(ax1, Bx[(8 + nt) * 64 + lane], acc[nt], 0, 0, 0);
    }

    // ---- H-part: 5 K-chunks ----
    if (withH) {
        const half8_t* Bp = (const half8_t*)Bpack;
        #pragma unroll
        for (int k = 0; k < KCH; ++k) {
            half8_t a = *(const half8_t*)(THall + ((size_t)k * N + node_a) * 32 + quad * 8);
            #pragma unroll
            for (int nt = 0; nt < 8; ++nt) {
                half8_t b = Bp[(k * 8 + nt) * 64 + lane];
                acc[nt] = __builtin_amdgcn_mfma_f32_16x16x32_f16(a, b, acc[nt], 0, 0, 0);
            }
        }
    }

    // ---- LSTM pointwise, register-local ----
    #pragma unroll
    for (int reg = 0; reg < 4; ++reg) {
        int node = nc0 + reg;
        if (node < N) {
            #pragma unroll
            for (int b = 0; b < 2; ++b) {
                int h = col + 16 * b;
                size_t idx = (size_t)node * 32 + h;
                float Co = Cst[idx];
                float I  = sigmoidf_(acc[0 + b][reg] + w_c[h] * Co);
                float F  = sigmoidf_(acc[2 + b][reg] + w_c[32 + h] * Co);
                float Tg = tanhf_(acc[4 + b][reg]);
                float Cn = F * Co + I * Tg;
                float O  = sigmoidf_(acc[6 + b][reg] + w_c[64 + h] * Cn);
                float Hn = O * tanhf_(Cn);
                Cst[idx] = Cn;
                THall[idx] = __float2half(Hn);
                if (doOut) Hbuf[(wave * 16 + quad * 4 + reg) * 33 + h] = fmaxf(Hn, 0.f);
            }
        } else if (doOut) {
            Hbuf[(wave * 16 + quad * 4 + reg) * 33 + col] = 0.f;
            Hbuf[(wave * 16 + quad * 4 + reg) * 33 + col + 16] = 0.f;
        }
    }

    // ---- fused output head (last timestep) ----
    if (doOut) {
        __syncthreads();
        int nl = tid >> 2, pp = (tid & 3) * 2;
        int node = base + nl;
        if (node < N) {
            float a0 = b_lin[pp], a1 = b_lin[pp + 1];
            const float* hp = Hbuf + nl * 33;
            #pragma unroll
            for (int h = 0; h < HID; ++h) {
                float hv = hp[h];
                a0 += hv * W_lin[pp * HID + h];
                a1 += hv * W_lin[(pp + 1) * HID + h];
            }
            float* op = out + (size_t)perm[node] * PERIODS + pp;
            op[0] = a0; op[1] = a1;
        }
    }
}

// ---------------- launch ----------------

extern "C" void kernel_launch(void* const* d_in, const int* in_sizes, int n_in,
                              void* d_out, int out_size, void* d_ws, size_t ws_size,
                              hipStream_t stream) {
    const float* xall  = (const float*)d_in[0];
    const int*   ei    = (const int*)d_in[1];
    const float* Wx    = (const float*)d_in[2];
    const float* Wh    = (const float*)d_in[3];
    const float* w_c   = (const float*)d_in[4];
    const float* bg    = (const float*)d_in[5];
    const float* W_lin = (const float*)d_in[6];
    const float* b_lin = (const float*)d_in[7];
    float* out = (float*)d_out;

    const int E = in_sizes[1] / 2;
    const int N = in_sizes[0] / (T_STEPS * F_IN);
    const int NT = (N + 255) / 256;
    const int* src = ei;
    const int* dst = ei + E;

    char* p = (char*)d_ws;
    auto carve = [&](size_t bytes) -> void* {
        void* r = (void*)p;
        p += (bytes + 255) & ~(size_t)255;
        return r;
    };
    // zero block: degi, cnt, fill, Cst
    char* zero_begin = p;
    int*    degi  = (int*)   carve((size_t)N * 4);
    int*    cnt   = (int*)   carve((size_t)N * 4);
    int*    fill  = (int*)   carve((size_t)N * 4);
    float*  Cst   = (float*) carve((size_t)N * HID * 4);
    size_t zero_bytes = (size_t)(p - zero_begin);
    __half* THall = (__half*)carve((size_t)KCH * N * HID * 2);
    int*    hist     = (int*)   carve((size_t)256 * NT * 4);
    int*    histbase = (int*)   carve(((size_t)256 * NT + 1) * 4);
    float*  dis      = (float*) carve((size_t)N * 4);
    int*    perm     = (int*)   carve((size_t)N * 4);
    int*    iperm    = (int*)   carve((size_t)N * 4);
    int*    cntp     = (int*)   carve((size_t)N * 4);
    int*    rowptr   = (int*)   carve((size_t)(N + 1) * 4);
    int2*   cv       = (int2*)  carve((size_t)E * 8);
    __half* xb       = (__half*)carve((size_t)N * 64 * 2);
    __half* TXB      = (__half*)carve((size_t)4 * N * 64 * 2);
    __half* Bpack    = (__half*)carve((size_t)KCH * 8 * 64 * 8 * 2);
    __half* Bxpack   = (__half*)carve((size_t)2 * 8 * 64 * 8 * 2);

    hipMemsetAsync(zero_begin, 0, zero_bytes, stream);

    const int TB = 256;
    const int gE = (E + TB - 1) / TB;
    k_count<<<gE, TB, 0, stream>>>(src, dst, degi, cnt, E);
    k_hist2<<<NT, TB, 0, stream>>>(cnt, hist, N, NT);
    k_scan<<<1, 1024, 0, stream>>>(hist, histbase, 256 * NT);
    k_permscat2<<<NT, TB, 0, stream>>>(cnt, degi, histbase, perm, iperm, cntp, dis, N, NT);
    k_scan<<<1, 1024, 0, stream>>>(cntp, rowptr, N);
    k_scatxt<<<gE, TB, 0, stream>>>(src, dst, dis, rowptr, iperm, fill, cv, xall, xb,
                                    Wh, Bpack, Wx, Bxpack, N, E);

    // batched x-phase Chebyshev terms over all timesteps (C = 64 halves, ES=4)
    __half* TXB0 = TXB;
    __half* TXB1 = TXB + (size_t)N * 64;
    __half* TXB2 = TXB + (size_t)2 * N * 64;
    __half* TXB3 = TXB + (size_t)3 * N * 64;
    const int lapx_grid = (N * 32 + TB - 1) / TB;   // W = 32 lanes/node
    k_lap_h<64, 4><<<lapx_grid, TB, 0, stream>>>(TXB0, xb,   nullptr, 1.f,  0.f, rowptr, cv, N);
    k_lap_h<64, 4><<<lapx_grid, TB, 0, stream>>>(TXB1, TXB0, xb,      2.f, -1.f, rowptr, cv, N);
    k_lap_h<64, 4><<<lapx_grid, TB, 0, stream>>>(TXB2, TXB1, TXB0,    2.f, -1.f, rowptr, cv, N);
    k_lap_h<64, 4><<<lapx_grid, TB, 0, stream>>>(TXB3, TXB2, TXB1,    2.f, -1.f, rowptr, cv, N);

    const int laph_grid = (N * 16 + TB - 1) / TB;   // W = 16 lanes/node
    const int step_grid = (N + NB - 1) / NB;
    __half* TH0 = THall;
    __half* TH1 = THall + (size_t)N * HID;
    __half* TH2 = THall + (size_t)2 * N * HID;
    __half* TH3 = THall + (size_t)3 * N * HID;
    __half* TH4 = THall + (size_t)4 * N * HID;

    for (int t = 0; t < T_STEPS; ++t) {
        if (t > 0) {   // H-terms all zero at t=0 (H0 = 0): skip laps
            k_lap_h<HID, 4><<<laph_grid, TB, 0, stream>>>(TH1, TH0, nullptr, 1.f,  0.f, rowptr, cv, N);
            k_lap_h<HID, 4><<<laph_grid, TB, 0, stream>>>(TH2, TH1, TH0,     2.f, -1.f, rowptr, cv, N);
            k_lap_h<HID, 4><<<laph_grid, TB, 0, stream>>>(TH3, TH2, TH1,     2.f, -1.f, rowptr, cv, N);
            k_lap_h<HID, 4><<<laph_grid, TB, 0, stream>>>(TH4, TH3, TH2,     2.f, -1.f, rowptr, cv, N);
        }
        k_stepM<<<step_grid, TB, 0, stream>>>(xb, TXB, THall, Cst, Bpack, Bxpack,
                                              w_c, bg, W_lin, b_lin, perm, out,
                                              t, (t > 0) ? 1 : 0,
                                              (t == T_STEPS - 1) ? 1 : 0, N);
    }
}